// Round 8
// baseline (489.311 us; speedup 1.0000x reference)
//
#include <hip/hip_runtime.h>
#include <hip/hip_bf16.h>

#define NPTS 262144
#define NC 64
#define NK 27
#define RPB 128          // rows per block (dwconv)
#define NBS 132          // padded int stride of transposed nbT rows

typedef __attribute__((ext_vector_type(8))) short bf16x8;
typedef __attribute__((ext_vector_type(4))) float f32x4;
typedef __attribute__((ext_vector_type(2))) float f32x2;

__device__ __forceinline__ unsigned cvtpk(float lo, float hi) {
    unsigned r;
    asm("v_cvt_pk_bf16_f32 %0, %1, %2" : "=v"(r) : "v"(lo), "v"(hi));
    return r;
}
__device__ __forceinline__ f32x2 up2(unsigned u) {
    f32x2 r;
    r.x = __uint_as_float(u << 16);
    r.y = __uint_as_float(u & 0xffff0000u);
    return r;
}

union BF { unsigned u[4]; bf16x8 v; };

// ---- Permuted bx storage layout -------------------------------------------
// ushort position p in a row maps to channel chan(p) = ((p>>1)&15) + ((p&1)<<4) + (p&32).
// dword d (d<16) packs channels (d, d+16); dword 16+d packs (d+32, d+48).

// Kernel A (MFMA): bx[r][perm] = bf16(feat[r]@W + b1). Also zeroes sentinel row.
__global__ __launch_bounds__(256) void gemm_mfma(const float* __restrict__ feat,
                                                 const float* __restrict__ W,
                                                 const float* __restrict__ b1,
                                                 ushort* __restrict__ bx,
                                                 uint* __restrict__ zrow) {
    __shared__ float Ws[NC * NC];
    __shared__ float b1S[NC];
    int t = threadIdx.x;
    if (zrow && blockIdx.x == 0 && t < 32) zrow[t] = 0u;   // 128B sentinel row
#pragma unroll
    for (int i = 0; i < 4; ++i)
        ((float4*)Ws)[t + i * 256] = ((const float4*)W)[t + i * 256];
    if (t < NC) b1S[t] = b1[t];
    __syncthreads();

    int lane = t & 63;
    int col = lane & 15;
    int kg = lane >> 4;
    int wid = blockIdx.x * 4 + (t >> 6);
    const int NWAVES = 2048 * 4;
    const int NTILES = NPTS / 16;

    BF Bf[2][4];
#pragma unroll
    for (int ks = 0; ks < 2; ++ks)
#pragma unroll
        for (int ct = 0; ct < 4; ++ct)
#pragma unroll
            for (int r = 0; r < 4; ++r) {
                float lo = Ws[(ks * 32 + kg * 8 + 2 * r) * NC + ct * 16 + col];
                float hi = Ws[(ks * 32 + kg * 8 + 2 * r + 1) * NC + ct * 16 + col];
                Bf[ks][ct].u[r] = cvtpk(lo, hi);
            }
    float bias[4];
#pragma unroll
    for (int ct = 0; ct < 4; ++ct) bias[ct] = b1S[ct * 16 + col];

    for (int tile = wid; tile < NTILES; tile += NWAVES) {
        long r0 = (long)tile * 16;
        const float* ap = feat + (r0 + col) * NC + kg * 8;
        float4 a0 = *(const float4*)(ap);
        float4 a1 = *(const float4*)(ap + 4);
        float4 a2 = *(const float4*)(ap + 32);
        float4 a3 = *(const float4*)(ap + 36);
        BF A0, A1;
        A0.u[0] = cvtpk(a0.x, a0.y); A0.u[1] = cvtpk(a0.z, a0.w);
        A0.u[2] = cvtpk(a1.x, a1.y); A0.u[3] = cvtpk(a1.z, a1.w);
        A1.u[0] = cvtpk(a2.x, a2.y); A1.u[1] = cvtpk(a2.z, a2.w);
        A1.u[2] = cvtpk(a3.x, a3.y); A1.u[3] = cvtpk(a3.z, a3.w);

        f32x4 acc[4];
#pragma unroll
        for (int ct = 0; ct < 4; ++ct) {
            acc[ct] = (f32x4){bias[ct], bias[ct], bias[ct], bias[ct]};
            acc[ct] = __builtin_amdgcn_mfma_f32_16x16x32_bf16(A0.v, Bf[0][ct].v, acc[ct], 0, 0, 0);
            acc[ct] = __builtin_amdgcn_mfma_f32_16x16x32_bf16(A1.v, Bf[1][ct].v, acc[ct], 0, 0, 0);
        }
#pragma unroll
        for (int i = 0; i < 4; ++i) {
            uint* bu = (uint*)(bx + (r0 + kg * 4 + i) * NC);
            bu[col]      = cvtpk(acc[0][i], acc[1][i]);
            bu[16 + col] = cvtpk(acc[2][i], acc[3][i]);
        }
    }
}

// Kernel B (SENT): k-outer, 4 rows x 8 ch/thread, manual 2-deep software
// pipeline: at iter k issue gathers for k+1, ds_read idx for k+2, consume k.
// Full unroll -> all rotating-buffer indices compile-time.
__global__ __launch_bounds__(256, 4) void dwconv_p(const float* __restrict__ feat,
                                                   const int* __restrict__ nb,
                                                   const float* __restrict__ b2,
                                                   const float* __restrict__ dw,
                                                   const ushort* __restrict__ bx,
                                                   float* __restrict__ out) {
    __shared__ int nbT[NK * NBS];
    __shared__ float dwS[NK * NC];   // permuted to bx storage order
    __shared__ float b2S[NC];
    int t = threadIdx.x;
    for (int i = t; i < NK * NC; i += 256) {
        int p = i & 63;
        int ch = ((p >> 1) & 15) + ((p & 1) << 4) + (p & 32);
        dwS[i] = dw[(i & ~63) + ch];
    }
    if (t < NC) b2S[t] = b2[t];

    // bijective chunked XCD swizzle (gridDim.x = 2048, %8 == 0)
    int b = blockIdx.x;
    int chunk = gridDim.x >> 3;
    int sb = (b & 7) * chunk + (b >> 3);

    // stage + transpose + sanitize (idx<0 -> sentinel row NPTS)
    const int* nsrc = nb + (size_t)sb * RPB * NK;
    for (int i = t; i < RPB * NK; i += 256) {
        int r = i / NK;
        int k = i - r * NK;
        int v = nsrc[i];
        nbT[k * NBS + r] = (v < 0) ? NPTS : v;
    }
    __syncthreads();

    int g = t >> 3;
    int q = t & 7;
    long row0 = (long)sb * RPB + g * 4;
    unsigned qo = (unsigned)q << 4;

    const char* bp = (const char*)bx;
    const int* nbase = nbT + g * 4;
    const f32x4* wq = (const f32x4*)dwS + q * 2;   // per k: wq[k*16], wq[k*16+1]

    f32x2 acc[4][4];
#pragma unroll
    for (int j = 0; j < 4; ++j)
#pragma unroll
        for (int i = 0; i < 4; ++i) acc[j][i] = (f32x2){0.f, 0.f};

    int4 idx[2];
    uint4 gb[2][4];

    // prologue: idx for k=0,1; gathers for k=0
    idx[0] = *(const int4*)(nbase + 0 * NBS);
    idx[1] = *(const int4*)(nbase + 1 * NBS);
    gb[0][0] = *(const uint4*)(bp + (((unsigned)idx[0].x << 7) + qo));
    gb[0][1] = *(const uint4*)(bp + (((unsigned)idx[0].y << 7) + qo));
    gb[0][2] = *(const uint4*)(bp + (((unsigned)idx[0].z << 7) + qo));
    gb[0][3] = *(const uint4*)(bp + (((unsigned)idx[0].w << 7) + qo));

#pragma unroll
    for (int k = 0; k < NK; ++k) {
        const int cur = k & 1, nxt = (k & 1) ^ 1;
        if (k + 1 < NK) {   // issue gathers for k+1 (stay in flight across consume)
            gb[nxt][0] = *(const uint4*)(bp + (((unsigned)idx[nxt].x << 7) + qo));
            gb[nxt][1] = *(const uint4*)(bp + (((unsigned)idx[nxt].y << 7) + qo));
            gb[nxt][2] = *(const uint4*)(bp + (((unsigned)idx[nxt].z << 7) + qo));
            gb[nxt][3] = *(const uint4*)(bp + (((unsigned)idx[nxt].w << 7) + qo));
        }
        if (k + 2 < NK)     // refill idx 2 ahead
            idx[cur] = *(const int4*)(nbase + (k + 2) * NBS);

        // weights for k (independent of the gather wait; compiler issues early)
        f32x4 wa = wq[k * 16];
        f32x4 wb = wq[k * 16 + 1];
        f32x2 w0 = {wa.x, wa.y}, w1 = {wa.z, wa.w};
        f32x2 w2 = {wb.x, wb.y}, w3 = {wb.z, wb.w};

        uint4 g0 = gb[cur][0], g1 = gb[cur][1], g2 = gb[cur][2], g3 = gb[cur][3];
        acc[0][0] += up2(g0.x) * w0; acc[0][1] += up2(g0.y) * w1;
        acc[0][2] += up2(g0.z) * w2; acc[0][3] += up2(g0.w) * w3;
        acc[1][0] += up2(g1.x) * w0; acc[1][1] += up2(g1.y) * w1;
        acc[1][2] += up2(g1.z) * w2; acc[1][3] += up2(g1.w) * w3;
        acc[2][0] += up2(g2.x) * w0; acc[2][1] += up2(g2.y) * w1;
        acc[2][2] += up2(g2.z) * w2; acc[2][3] += up2(g2.w) * w3;
        acc[3][0] += up2(g3.x) * w0; acc[3][1] += up2(g3.y) * w1;
        acc[3][2] += up2(g3.z) * w2; acc[3][3] += up2(g3.w) * w3;
    }

    int lo_c0 = (q < 4) ? 4 * q : 16 + 4 * q;
    int hi_c0 = lo_c0 + 16;
#pragma unroll
    for (int j = 0; j < 4; ++j) {
        long row = row0 + j;
        const float* fp = feat + row * NC;
        float4 flo = *(const float4*)(fp + lo_c0);
        float4 fhi = *(const float4*)(fp + hi_c0);
        float4 olo = make_float4(acc[j][0].x + flo.x + b2S[lo_c0 + 0],
                                 acc[j][1].x + flo.y + b2S[lo_c0 + 1],
                                 acc[j][2].x + flo.z + b2S[lo_c0 + 2],
                                 acc[j][3].x + flo.w + b2S[lo_c0 + 3]);
        float4 ohi = make_float4(acc[j][0].y + fhi.x + b2S[hi_c0 + 0],
                                 acc[j][1].y + fhi.y + b2S[hi_c0 + 1],
                                 acc[j][2].y + fhi.z + b2S[hi_c0 + 2],
                                 acc[j][3].y + fhi.w + b2S[hi_c0 + 3]);
        *(float4*)(out + row * NC + lo_c0) = olo;
        *(float4*)(out + row * NC + hi_c0) = ohi;
    }
}

// Fallback (no sentinel space in ws): simple masked k-loop (R7 form).
__global__ __launch_bounds__(256, 5) void dwconv_f(const float* __restrict__ feat,
                                                   const int* __restrict__ nb,
                                                   const float* __restrict__ b2,
                                                   const float* __restrict__ dw,
                                                   const ushort* __restrict__ bx,
                                                   float* __restrict__ out) {
    __shared__ int nbT[NK * NBS];
    __shared__ float dwS[NK * NC];
    __shared__ float b2S[NC];
    int t = threadIdx.x;
    for (int i = t; i < NK * NC; i += 256) {
        int p = i & 63;
        int ch = ((p >> 1) & 15) + ((p & 1) << 4) + (p & 32);
        dwS[i] = dw[(i & ~63) + ch];
    }
    if (t < NC) b2S[t] = b2[t];
    int b = blockIdx.x;
    int chunk = gridDim.x >> 3;
    int sb = (b & 7) * chunk + (b >> 3);
    const int* nsrc = nb + (size_t)sb * RPB * NK;
    for (int i = t; i < RPB * NK; i += 256) {
        int r = i / NK;
        int k = i - r * NK;
        nbT[k * NBS + r] = nsrc[i];
    }
    __syncthreads();

    int g = t >> 3, q = t & 7;
    long row0 = (long)sb * RPB + g * 4;
    unsigned qo = (unsigned)q << 4;
    f32x2 acc[4][4];
#pragma unroll
    for (int j = 0; j < 4; ++j)
#pragma unroll
        for (int i = 0; i < 4; ++i) acc[j][i] = (f32x2){0.f, 0.f};
    const char* bp = (const char*)bx;
    const int* nbase = nbT + g * 4;
    const f32x2* wbase = (const f32x2*)dwS + q * 4;

#pragma unroll 3
    for (int k = 0; k < NK; ++k) {
        int4 idx = *(const int4*)(nbase + k * NBS);
        int sx = max(idx.x, 0), sy = max(idx.y, 0), sz = max(idx.z, 0), sw = max(idx.w, 0);
        uint4 g0 = *(const uint4*)(bp + (((unsigned)sx << 7) + qo));
        uint4 g1 = *(const uint4*)(bp + (((unsigned)sy << 7) + qo));
        uint4 g2 = *(const uint4*)(bp + (((unsigned)sz << 7) + qo));
        uint4 g3 = *(const uint4*)(bp + (((unsigned)sw << 7) + qo));
        unsigned m0 = idx.x >= 0 ? 0xffffffffu : 0u;
        unsigned m1 = idx.y >= 0 ? 0xffffffffu : 0u;
        unsigned m2 = idx.z >= 0 ? 0xffffffffu : 0u;
        unsigned m3 = idx.w >= 0 ? 0xffffffffu : 0u;
        g0.x &= m0; g0.y &= m0; g0.z &= m0; g0.w &= m0;
        g1.x &= m1; g1.y &= m1; g1.z &= m1; g1.w &= m1;
        g2.x &= m2; g2.y &= m2; g2.z &= m2; g2.w &= m2;
        g3.x &= m3; g3.y &= m3; g3.z &= m3; g3.w &= m3;
        f32x2 w0 = wbase[k * 32 + 0], w1 = wbase[k * 32 + 1];
        f32x2 w2 = wbase[k * 32 + 2], w3 = wbase[k * 32 + 3];
        acc[0][0] += up2(g0.x) * w0; acc[0][1] += up2(g0.y) * w1;
        acc[0][2] += up2(g0.z) * w2; acc[0][3] += up2(g0.w) * w3;
        acc[1][0] += up2(g1.x) * w0; acc[1][1] += up2(g1.y) * w1;
        acc[1][2] += up2(g1.z) * w2; acc[1][3] += up2(g1.w) * w3;
        acc[2][0] += up2(g2.x) * w0; acc[2][1] += up2(g2.y) * w1;
        acc[2][2] += up2(g2.z) * w2; acc[2][3] += up2(g2.w) * w3;
        acc[3][0] += up2(g3.x) * w0; acc[3][1] += up2(g3.y) * w1;
        acc[3][2] += up2(g3.z) * w2; acc[3][3] += up2(g3.w) * w3;
    }

    int lo_c0 = (q < 4) ? 4 * q : 16 + 4 * q;
    int hi_c0 = lo_c0 + 16;
#pragma unroll
    for (int j = 0; j < 4; ++j) {
        long row = row0 + j;
        const float* fp = feat + row * NC;
        float4 flo = *(const float4*)(fp + lo_c0);
        float4 fhi = *(const float4*)(fp + hi_c0);
        float4 olo = make_float4(acc[j][0].x + flo.x + b2S[lo_c0 + 0],
                                 acc[j][1].x + flo.y + b2S[lo_c0 + 1],
                                 acc[j][2].x + flo.z + b2S[lo_c0 + 2],
                                 acc[j][3].x + flo.w + b2S[lo_c0 + 3]);
        float4 ohi = make_float4(acc[j][0].y + fhi.x + b2S[hi_c0 + 0],
                                 acc[j][1].y + fhi.y + b2S[hi_c0 + 1],
                                 acc[j][2].y + fhi.z + b2S[hi_c0 + 2],
                                 acc[j][3].y + fhi.w + b2S[hi_c0 + 3]);
        *(float4*)(out + row * NC + lo_c0) = olo;
        *(float4*)(out + row * NC + hi_c0) = ohi;
    }
}

extern "C" void kernel_launch(void* const* d_in, const int* in_sizes, int n_in,
                              void* d_out, int out_size, void* d_ws, size_t ws_size,
                              hipStream_t stream) {
    const float* feat = (const float*)d_in[0];
    const int*   nb   = (const int*)d_in[1];
    const float* W    = (const float*)d_in[2];
    const float* b1   = (const float*)d_in[3];
    const float* b2   = (const float*)d_in[4];
    const float* dw   = (const float*)d_in[5];
    float* out = (float*)d_out;
    ushort* bx = (ushort*)d_ws;   // (NPTS+1) x 64 bf16 (permuted), sentinel last

    bool sent = ws_size >= (size_t)(NPTS + 1) * NC * sizeof(ushort);
    uint* zrow = sent ? (uint*)(bx + (size_t)NPTS * NC) : nullptr;

    gemm_mfma<<<2048, 256, 0, stream>>>(feat, W, b1, bx, zrow);
    if (sent)
        dwconv_p<<<NPTS / RPB, 256, 0, stream>>>(feat, nb, b2, dw, bx, out);
    else
        dwconv_f<<<NPTS / RPB, 256, 0, stream>>>(feat, nb, b2, dw, bx, out);
}

// Round 10
// 452.469 us; speedup vs baseline: 1.0814x; 1.0814x over previous
//
#include <hip/hip_runtime.h>
#include <hip/hip_bf16.h>

#define NPTS 262144
#define NC 64
#define NK 27
#define RPB 128          // rows per block (dwconv)
#define NBS 132          // padded int stride of transposed nbT rows

typedef __attribute__((ext_vector_type(8))) short bf16x8;
typedef __attribute__((ext_vector_type(4))) float f32x4;
typedef __attribute__((ext_vector_type(2))) float f32x2;

__device__ __forceinline__ unsigned cvtpk(float lo, float hi) {
    unsigned r;
    asm("v_cvt_pk_bf16_f32 %0, %1, %2" : "=v"(r) : "v"(lo), "v"(hi));
    return r;
}
__device__ __forceinline__ f32x2 up2(unsigned u) {
    f32x2 r;
    r.x = __uint_as_float(u << 16);
    r.y = __uint_as_float(u & 0xffff0000u);
    return r;
}

union BF { unsigned u[4]; bf16x8 v; };

// ---- Permuted bx storage layout -------------------------------------------
// ushort position p in a row maps to channel chan(p) = ((p>>1)&15) + ((p&1)<<4) + (p&32).
// dword d (d<16) packs channels (d, d+16); dword 16+d packs (d+32, d+48).

// Kernel A (MFMA): bx[r][perm] = bf16(feat[r]@W + b1). Also zeroes sentinel row.
__global__ __launch_bounds__(256) void gemm_mfma(const float* __restrict__ feat,
                                                 const float* __restrict__ W,
                                                 const float* __restrict__ b1,
                                                 ushort* __restrict__ bx,
                                                 uint* __restrict__ zrow) {
    __shared__ float Ws[NC * NC];
    __shared__ float b1S[NC];
    int t = threadIdx.x;
    if (zrow && blockIdx.x == 0 && t < 32) zrow[t] = 0u;   // 128B sentinel row
#pragma unroll
    for (int i = 0; i < 4; ++i)
        ((float4*)Ws)[t + i * 256] = ((const float4*)W)[t + i * 256];
    if (t < NC) b1S[t] = b1[t];
    __syncthreads();

    int lane = t & 63;
    int col = lane & 15;
    int kg = lane >> 4;
    int wid = blockIdx.x * 4 + (t >> 6);
    const int NWAVES = 2048 * 4;
    const int NTILES = NPTS / 16;

    BF Bf[2][4];
#pragma unroll
    for (int ks = 0; ks < 2; ++ks)
#pragma unroll
        for (int ct = 0; ct < 4; ++ct)
#pragma unroll
            for (int r = 0; r < 4; ++r) {
                float lo = Ws[(ks * 32 + kg * 8 + 2 * r) * NC + ct * 16 + col];
                float hi = Ws[(ks * 32 + kg * 8 + 2 * r + 1) * NC + ct * 16 + col];
                Bf[ks][ct].u[r] = cvtpk(lo, hi);
            }
    float bias[4];
#pragma unroll
    for (int ct = 0; ct < 4; ++ct) bias[ct] = b1S[ct * 16 + col];

    for (int tile = wid; tile < NTILES; tile += NWAVES) {
        long r0 = (long)tile * 16;
        const float* ap = feat + (r0 + col) * NC + kg * 8;
        float4 a0 = *(const float4*)(ap);
        float4 a1 = *(const float4*)(ap + 4);
        float4 a2 = *(const float4*)(ap + 32);
        float4 a3 = *(const float4*)(ap + 36);
        BF A0, A1;
        A0.u[0] = cvtpk(a0.x, a0.y); A0.u[1] = cvtpk(a0.z, a0.w);
        A0.u[2] = cvtpk(a1.x, a1.y); A0.u[3] = cvtpk(a1.z, a1.w);
        A1.u[0] = cvtpk(a2.x, a2.y); A1.u[1] = cvtpk(a2.z, a2.w);
        A1.u[2] = cvtpk(a3.x, a3.y); A1.u[3] = cvtpk(a3.z, a3.w);

        f32x4 acc[4];
#pragma unroll
        for (int ct = 0; ct < 4; ++ct) {
            acc[ct] = (f32x4){bias[ct], bias[ct], bias[ct], bias[ct]};
            acc[ct] = __builtin_amdgcn_mfma_f32_16x16x32_bf16(A0.v, Bf[0][ct].v, acc[ct], 0, 0, 0);
            acc[ct] = __builtin_amdgcn_mfma_f32_16x16x32_bf16(A1.v, Bf[1][ct].v, acc[ct], 0, 0, 0);
        }
#pragma unroll
        for (int i = 0; i < 4; ++i) {
            uint* bu = (uint*)(bx + (r0 + kg * 4 + i) * NC);
            bu[col]      = cvtpk(acc[0][i], acc[1][i]);
            bu[16 + col] = cvtpk(acc[2][i], acc[3][i]);
        }
    }
}

// Kernel B (SENT): k-outer, 4 rows x 8 ch/thread, explicit 2-deep software
// pipeline with NAMED double-buffer registers only (no arrays -> no scratch).
__global__ __launch_bounds__(256, 4) void dwconv_p(const float* __restrict__ feat,
                                                   const int* __restrict__ nb,
                                                   const float* __restrict__ b2,
                                                   const float* __restrict__ dw,
                                                   const ushort* __restrict__ bx,
                                                   float* __restrict__ out) {
    __shared__ int nbT[NK * NBS];
    __shared__ float dwS[NK * NC];   // permuted to bx storage order
    __shared__ float b2S[NC];
    int t = threadIdx.x;
    for (int i = t; i < NK * NC; i += 256) {
        int p = i & 63;
        int ch = ((p >> 1) & 15) + ((p & 1) << 4) + (p & 32);
        dwS[i] = dw[(i & ~63) + ch];
    }
    if (t < NC) b2S[t] = b2[t];

    // bijective chunked XCD swizzle (gridDim.x = 2048, %8 == 0)
    int b = blockIdx.x;
    int chunk = gridDim.x >> 3;
    int sb = (b & 7) * chunk + (b >> 3);

    // stage + transpose + sanitize (idx<0 -> sentinel row NPTS)
    const int* nsrc = nb + (size_t)sb * RPB * NK;
    for (int i = t; i < RPB * NK; i += 256) {
        int r = i / NK;
        int k = i - r * NK;
        int v = nsrc[i];
        nbT[k * NBS + r] = (v < 0) ? NPTS : v;
    }
    __syncthreads();

    int g = t >> 3;
    int q = t & 7;
    long row0 = (long)sb * RPB + g * 4;
    unsigned qo = (unsigned)q << 4;

    const char* bp = (const char*)bx;
    const int* nbase = nbT + g * 4;
    const f32x4* wq = (const f32x4*)dwS + q * 2;   // per k: wq[k*16], wq[k*16+1]

    f32x2 acc00 = {0,0}, acc01 = {0,0}, acc02 = {0,0}, acc03 = {0,0};
    f32x2 acc10 = {0,0}, acc11 = {0,0}, acc12 = {0,0}, acc13 = {0,0};
    f32x2 acc20 = {0,0}, acc21 = {0,0}, acc22 = {0,0}, acc23 = {0,0};
    f32x2 acc30 = {0,0}, acc31 = {0,0}, acc32 = {0,0}, acc33 = {0,0};

#define GATHER4(d0, d1, d2, d3, ii)                                      \
    d0 = *(const uint4*)(bp + (((unsigned)(ii).x << 7) + qo));           \
    d1 = *(const uint4*)(bp + (((unsigned)(ii).y << 7) + qo));           \
    d2 = *(const uint4*)(bp + (((unsigned)(ii).z << 7) + qo));           \
    d3 = *(const uint4*)(bp + (((unsigned)(ii).w << 7) + qo))

#define CONSUME(g0, g1, g2, g3, kk)                                      \
    {                                                                    \
        f32x4 wa = wq[(kk) * 16];                                        \
        f32x4 wb = wq[(kk) * 16 + 1];                                    \
        f32x2 w0 = {wa.x, wa.y}, w1 = {wa.z, wa.w};                      \
        f32x2 w2 = {wb.x, wb.y}, w3 = {wb.z, wb.w};                      \
        acc00 += up2(g0.x) * w0; acc01 += up2(g0.y) * w1;                \
        acc02 += up2(g0.z) * w2; acc03 += up2(g0.w) * w3;                \
        acc10 += up2(g1.x) * w0; acc11 += up2(g1.y) * w1;                \
        acc12 += up2(g1.z) * w2; acc13 += up2(g1.w) * w3;                \
        acc20 += up2(g2.x) * w0; acc21 += up2(g2.y) * w1;                \
        acc22 += up2(g2.z) * w2; acc23 += up2(g2.w) * w3;                \
        acc30 += up2(g3.x) * w0; acc31 += up2(g3.y) * w1;                \
        acc32 += up2(g3.z) * w2; acc33 += up2(g3.w) * w3;                \
    }

    int4 iA = *(const int4*)(nbase + 0 * NBS);
    int4 iB = *(const int4*)(nbase + 1 * NBS);
    uint4 a0, a1, a2, a3, b0, b1, b2v, b3;
    GATHER4(a0, a1, a2, a3, iA);            // k=0 in flight

#pragma unroll
    for (int k = 0; k < NK - 1; k += 2) {   // 13 pairs: k = 0,2,...,24
        GATHER4(b0, b1, b2v, b3, iB);       // issue k+1
        iA = *(const int4*)(nbase + (k + 2) * NBS);     // k+2 <= 26 always
        CONSUME(a0, a1, a2, a3, k);         // waits vmcnt(4): b stays in flight
        GATHER4(a0, a1, a2, a3, iA);        // issue k+2
        if (k + 3 < NK) iB = *(const int4*)(nbase + (k + 3) * NBS);
        CONSUME(b0, b1, b2v, b3, k + 1);
    }
    CONSUME(a0, a1, a2, a3, NK - 1);        // tail k=26
#undef GATHER4
#undef CONSUME

    int lo_c0 = (q < 4) ? 4 * q : 16 + 4 * q;
    int hi_c0 = lo_c0 + 16;
    {
        const float* fp = feat + row0 * NC;
        float4 flo, fhi, olo, ohi;
#define EPI(J, A0_, A1_, A2_, A3_)                                       \
        flo = *(const float4*)(fp + (J) * NC + lo_c0);                   \
        fhi = *(const float4*)(fp + (J) * NC + hi_c0);                   \
        olo = make_float4(A0_.x + flo.x + b2S[lo_c0 + 0],                \
                          A1_.x + flo.y + b2S[lo_c0 + 1],                \
                          A2_.x + flo.z + b2S[lo_c0 + 2],                \
                          A3_.x + flo.w + b2S[lo_c0 + 3]);               \
        ohi = make_float4(A0_.y + fhi.x + b2S[hi_c0 + 0],                \
                          A1_.y + fhi.y + b2S[hi_c0 + 1],                \
                          A2_.y + fhi.z + b2S[hi_c0 + 2],                \
                          A3_.y + fhi.w + b2S[hi_c0 + 3]);               \
        *(float4*)(out + (row0 + (J)) * NC + lo_c0) = olo;               \
        *(float4*)(out + (row0 + (J)) * NC + hi_c0) = ohi
        EPI(0, acc00, acc01, acc02, acc03);
        EPI(1, acc10, acc11, acc12, acc13);
        EPI(2, acc20, acc21, acc22, acc23);
        EPI(3, acc30, acc31, acc32, acc33);
#undef EPI
    }
}

// Fallback (no sentinel space in ws): simple masked k-loop (R7 form).
__global__ __launch_bounds__(256, 5) void dwconv_f(const float* __restrict__ feat,
                                                   const int* __restrict__ nb,
                                                   const float* __restrict__ b2,
                                                   const float* __restrict__ dw,
                                                   const ushort* __restrict__ bx,
                                                   float* __restrict__ out) {
    __shared__ int nbT[NK * NBS];
    __shared__ float dwS[NK * NC];
    __shared__ float b2S[NC];
    int t = threadIdx.x;
    for (int i = t; i < NK * NC; i += 256) {
        int p = i & 63;
        int ch = ((p >> 1) & 15) + ((p & 1) << 4) + (p & 32);
        dwS[i] = dw[(i & ~63) + ch];
    }
    if (t < NC) b2S[t] = b2[t];
    int b = blockIdx.x;
    int chunk = gridDim.x >> 3;
    int sb = (b & 7) * chunk + (b >> 3);
    const int* nsrc = nb + (size_t)sb * RPB * NK;
    for (int i = t; i < RPB * NK; i += 256) {
        int r = i / NK;
        int k = i - r * NK;
        nbT[k * NBS + r] = nsrc[i];
    }
    __syncthreads();

    int g = t >> 3, q = t & 7;
    long row0 = (long)sb * RPB + g * 4;
    unsigned qo = (unsigned)q << 4;
    f32x2 acc[4][4];
#pragma unroll
    for (int j = 0; j < 4; ++j)
#pragma unroll
        for (int i = 0; i < 4; ++i) acc[j][i] = (f32x2){0.f, 0.f};
    const char* bp = (const char*)bx;
    const int* nbase = nbT + g * 4;
    const f32x2* wbase = (const f32x2*)dwS + q * 4;

#pragma unroll 3
    for (int k = 0; k < NK; ++k) {
        int4 idx = *(const int4*)(nbase + k * NBS);
        int sx = max(idx.x, 0), sy = max(idx.y, 0), sz = max(idx.z, 0), sw = max(idx.w, 0);
        uint4 g0 = *(const uint4*)(bp + (((unsigned)sx << 7) + qo));
        uint4 g1 = *(const uint4*)(bp + (((unsigned)sy << 7) + qo));
        uint4 g2 = *(const uint4*)(bp + (((unsigned)sz << 7) + qo));
        uint4 g3 = *(const uint4*)(bp + (((unsigned)sw << 7) + qo));
        unsigned m0 = idx.x >= 0 ? 0xffffffffu : 0u;
        unsigned m1 = idx.y >= 0 ? 0xffffffffu : 0u;
        unsigned m2 = idx.z >= 0 ? 0xffffffffu : 0u;
        unsigned m3 = idx.w >= 0 ? 0xffffffffu : 0u;
        g0.x &= m0; g0.y &= m0; g0.z &= m0; g0.w &= m0;
        g1.x &= m1; g1.y &= m1; g1.z &= m1; g1.w &= m1;
        g2.x &= m2; g2.y &= m2; g2.z &= m2; g2.w &= m2;
        g3.x &= m3; g3.y &= m3; g3.z &= m3; g3.w &= m3;
        f32x2 w0 = wbase[k * 32 + 0], w1 = wbase[k * 32 + 1];
        f32x2 w2 = wbase[k * 32 + 2], w3 = wbase[k * 32 + 3];
        acc[0][0] += up2(g0.x) * w0; acc[0][1] += up2(g0.y) * w1;
        acc[0][2] += up2(g0.z) * w2; acc[0][3] += up2(g0.w) * w3;
        acc[1][0] += up2(g1.x) * w0; acc[1][1] += up2(g1.y) * w1;
        acc[1][2] += up2(g1.z) * w2; acc[1][3] += up2(g1.w) * w3;
        acc[2][0] += up2(g2.x) * w0; acc[2][1] += up2(g2.y) * w1;
        acc[2][2] += up2(g2.z) * w2; acc[2][3] += up2(g2.w) * w3;
        acc[3][0] += up2(g3.x) * w0; acc[3][1] += up2(g3.y) * w1;
        acc[3][2] += up2(g3.z) * w2; acc[3][3] += up2(g3.w) * w3;
    }

    int lo_c0 = (q < 4) ? 4 * q : 16 + 4 * q;
    int hi_c0 = lo_c0 + 16;
#pragma unroll
    for (int j = 0; j < 4; ++j) {
        long row = row0 + j;
        const float* fp = feat + row * NC;
        float4 flo = *(const float4*)(fp + lo_c0);
        float4 fhi = *(const float4*)(fp + hi_c0);
        float4 olo = make_float4(acc[j][0].x + flo.x + b2S[lo_c0 + 0],
                                 acc[j][1].x + flo.y + b2S[lo_c0 + 1],
                                 acc[j][2].x + flo.z + b2S[lo_c0 + 2],
                                 acc[j][3].x + flo.w + b2S[lo_c0 + 3]);
        float4 ohi = make_float4(acc[j][0].y + fhi.x + b2S[hi_c0 + 0],
                                 acc[j][1].y + fhi.y + b2S[hi_c0 + 1],
                                 acc[j][2].y + fhi.z + b2S[hi_c0 + 2],
                                 acc[j][3].y + fhi.w + b2S[hi_c0 + 3]);
        *(float4*)(out + row * NC + lo_c0) = olo;
        *(float4*)(out + row * NC + hi_c0) = ohi;
    }
}

extern "C" void kernel_launch(void* const* d_in, const int* in_sizes, int n_in,
                              void* d_out, int out_size, void* d_ws, size_t ws_size,
                              hipStream_t stream) {
    const float* feat = (const float*)d_in[0];
    const int*   nb   = (const int*)d_in[1];
    const float* W    = (const float*)d_in[2];
    const float* b1   = (const float*)d_in[3];
    const float* b2   = (const float*)d_in[4];
    const float* dw   = (const float*)d_in[5];
    float* out = (float*)d_out;
    ushort* bx = (ushort*)d_ws;   // (NPTS+1) x 64 bf16 (permuted), sentinel last

    bool sent = ws_size >= (size_t)(NPTS + 1) * NC * sizeof(ushort);
    uint* zrow = sent ? (uint*)(bx + (size_t)NPTS * NC) : nullptr;

    gemm_mfma<<<2048, 256, 0, stream>>>(feat, W, b1, bx, zrow);
    if (sent)
        dwconv_p<<<NPTS / RPB, 256, 0, stream>>>(feat, nb, b2, dw, bx, out);
    else
        dwconv_f<<<NPTS / RPB, 256, 0, stream>>>(feat, nb, b2, dw, bx, out);
}

// Round 13
// 204.861 us; speedup vs baseline: 2.3885x; 2.2087x over previous
//
#include <hip/hip_runtime.h>
#include <hip/hip_bf16.h>

#define NPTS 262144
#define NC 64
#define NK 27
#define NBS2 28          // padded int stride of nbS rows

typedef __attribute__((ext_vector_type(8))) short bf16x8;
typedef __attribute__((ext_vector_type(4))) float f32x4;
typedef __attribute__((ext_vector_type(2))) float f32x2;

__device__ __forceinline__ unsigned cvtpk(float lo, float hi) {
    unsigned r;
    asm("v_cvt_pk_bf16_f32 %0, %1, %2" : "=v"(r) : "v"(lo), "v"(hi));
    return r;
}
__device__ __forceinline__ f32x2 up2(unsigned u) {
    f32x2 r;
    r.x = __uint_as_float(u << 16);
    r.y = __uint_as_float(u & 0xffff0000u);
    return r;
}

union BF { unsigned u[4]; bf16x8 v; };

// ---- Permuted bx storage layout -------------------------------------------
// ushort position p in a row maps to channel chan(p) = ((p>>1)&15) + ((p&1)<<4) + (p&32).
// dword d (d<16) packs channels (d, d+16); dword 16+d packs (d+32, d+48).

// Kernel A (MFMA): bx[r][perm] = bf16(feat[r]@W + b1). Also zeroes sentinel row.
__global__ __launch_bounds__(256) void gemm_mfma(const float* __restrict__ feat,
                                                 const float* __restrict__ W,
                                                 const float* __restrict__ b1,
                                                 ushort* __restrict__ bx,
                                                 uint* __restrict__ zrow) {
    __shared__ float Ws[NC * NC];
    __shared__ float b1S[NC];
    int t = threadIdx.x;
    if (zrow && blockIdx.x == 0 && t < 32) zrow[t] = 0u;   // 128B sentinel row
#pragma unroll
    for (int i = 0; i < 4; ++i)
        ((float4*)Ws)[t + i * 256] = ((const float4*)W)[t + i * 256];
    if (t < NC) b1S[t] = b1[t];
    __syncthreads();

    int lane = t & 63;
    int col = lane & 15;
    int kg = lane >> 4;
    int wid = blockIdx.x * 4 + (t >> 6);
    const int NWAVES = 2048 * 4;
    const int NTILES = NPTS / 16;

    BF Bf[2][4];
#pragma unroll
    for (int ks = 0; ks < 2; ++ks)
#pragma unroll
        for (int ct = 0; ct < 4; ++ct)
#pragma unroll
            for (int r = 0; r < 4; ++r) {
                float lo = Ws[(ks * 32 + kg * 8 + 2 * r) * NC + ct * 16 + col];
                float hi = Ws[(ks * 32 + kg * 8 + 2 * r + 1) * NC + ct * 16 + col];
                Bf[ks][ct].u[r] = cvtpk(lo, hi);
            }
    float bias[4];
#pragma unroll
    for (int ct = 0; ct < 4; ++ct) bias[ct] = b1S[ct * 16 + col];

    for (int tile = wid; tile < NTILES; tile += NWAVES) {
        long r0 = (long)tile * 16;
        const float* ap = feat + (r0 + col) * NC + kg * 8;
        float4 a0 = *(const float4*)(ap);
        float4 a1 = *(const float4*)(ap + 4);
        float4 a2 = *(const float4*)(ap + 32);
        float4 a3 = *(const float4*)(ap + 36);
        BF A0, A1;
        A0.u[0] = cvtpk(a0.x, a0.y); A0.u[1] = cvtpk(a0.z, a0.w);
        A0.u[2] = cvtpk(a1.x, a1.y); A0.u[3] = cvtpk(a1.z, a1.w);
        A1.u[0] = cvtpk(a2.x, a2.y); A1.u[1] = cvtpk(a2.z, a2.w);
        A1.u[2] = cvtpk(a3.x, a3.y); A1.u[3] = cvtpk(a3.z, a3.w);

        f32x4 acc[4];
#pragma unroll
        for (int ct = 0; ct < 4; ++ct) {
            acc[ct] = (f32x4){bias[ct], bias[ct], bias[ct], bias[ct]};
            acc[ct] = __builtin_amdgcn_mfma_f32_16x16x32_bf16(A0.v, Bf[0][ct].v, acc[ct], 0, 0, 0);
            acc[ct] = __builtin_amdgcn_mfma_f32_16x16x32_bf16(A1.v, Bf[1][ct].v, acc[ct], 0, 0, 0);
        }
#pragma unroll
        for (int i = 0; i < 4; ++i) {
            uint* bu = (uint*)(bx + (r0 + kg * 4 + i) * NC);
            bu[col]      = cvtpk(acc[0][i], acc[1][i]);
            bu[16 + col] = cvtpk(acc[2][i], acc[3][i]);
        }
    }
}

// Kernel B (sentinel): 8 lanes/row x 32 rows/block. Sanitized idx in LDS
// (idx<0 -> NPTS zero row) -> no validity VALU, wave-uniform weight reads
// (no bank conflicts). 1-deep ping-pong gather prefetch via two NAMED uint4s
// (k+=2 unroll, no register copies, no arrays -> no scratch).
__global__ __launch_bounds__(256, 8) void dwconv_s(const float* __restrict__ feat,
                                                   const int* __restrict__ nb,
                                                   const float* __restrict__ b2,
                                                   const float* __restrict__ dw,
                                                   const ushort* __restrict__ bx,
                                                   float* __restrict__ out) {
    __shared__ float dwS[NK * NC];   // permuted to bx storage order
    __shared__ float b2S[NC];
    __shared__ int nbS[32 * NBS2];
    int t = threadIdx.x;
    for (int i = t; i < NK * NC; i += 256) {
        int p = i & 63;
        int ch = ((p >> 1) & 15) + ((p & 1) << 4) + (p & 32);
        dwS[i] = dw[(i & ~63) + ch];
    }
    if (t < NC) b2S[t] = b2[t];

    // bijective chunked XCD swizzle (gridDim.x = 8192, %8 == 0)
    int b = blockIdx.x;
    int chunk = gridDim.x >> 3;
    int sb = (b & 7) * chunk + (b >> 3);

    // stage + sanitize this block's 32x27 neighbor tile
    const int* nsrc = nb + (size_t)sb * 32 * NK;
    for (int i = t; i < 32 * NK; i += 256) {
        int r = i / NK;
        int k = i - r * NK;
        int v = nsrc[i];
        nbS[r * NBS2 + k] = (v < 0) ? NPTS : v;
    }
    __syncthreads();

    int r = t >> 3;
    int q = t & 7;
    long row = (long)sb * 32 + r;
    unsigned qo = (unsigned)q << 4;

    const char* bp = (const char*)bx;
    const int* nrow = nbS + r * NBS2;
    const f32x4* wq = (const f32x4*)dwS + q * 2;   // per k: wq[k*16], wq[k*16+1]

    f32x2 acc0 = {0,0}, acc1 = {0,0}, acc2 = {0,0}, acc3 = {0,0};

#define GATHER(d, ii) d = *(const uint4*)(bp + (((unsigned)(ii) << 7) + qo))
#define CONSUME(gg, kk)                                                  \
    {                                                                    \
        f32x4 wa = wq[(kk) * 16];                                        \
        f32x4 wb = wq[(kk) * 16 + 1];                                    \
        acc0 += up2(gg.x) * (f32x2){wa.x, wa.y};                         \
        acc1 += up2(gg.y) * (f32x2){wa.z, wa.w};                         \
        acc2 += up2(gg.z) * (f32x2){wb.x, wb.y};                         \
        acc3 += up2(gg.w) * (f32x2){wb.z, wb.w};                         \
    }

    int iA = nrow[0], iB;
    uint4 ga, gb;
    GATHER(ga, iA);                      // k=0 in flight

#pragma unroll
    for (int k = 0; k < NK - 1; k += 2) {   // k = 0,2,...,24
        iB = nrow[k + 1];
        GATHER(gb, iB);                  // issue k+1
        CONSUME(ga, k);                  // waits ga; gb stays in flight
        iA = nrow[k + 2];                // k+2 <= 26 always
        GATHER(ga, iA);                  // issue k+2
        CONSUME(gb, k + 1);
    }
    CONSUME(ga, NK - 1);                 // tail k=26
#undef GATHER
#undef CONSUME

    int lo_c0 = (q < 4) ? 4 * q : 16 + 4 * q;
    int hi_c0 = lo_c0 + 16;
    const float* fp = feat + row * NC;
    float4 flo = *(const float4*)(fp + lo_c0);
    float4 fhi = *(const float4*)(fp + hi_c0);
    float4 olo = make_float4(acc0.x + flo.x + b2S[lo_c0 + 0],
                             acc1.x + flo.y + b2S[lo_c0 + 1],
                             acc2.x + flo.z + b2S[lo_c0 + 2],
                             acc3.x + flo.w + b2S[lo_c0 + 3]);
    float4 ohi = make_float4(acc0.y + fhi.x + b2S[hi_c0 + 0],
                             acc1.y + fhi.y + b2S[hi_c0 + 1],
                             acc2.y + fhi.z + b2S[hi_c0 + 2],
                             acc3.y + fhi.w + b2S[hi_c0 + 3]);
    *(float4*)(out + row * NC + lo_c0) = olo;
    *(float4*)(out + row * NC + hi_c0) = ohi;
}

// Fallback (no sentinel space in ws): masked k-loop, R6 form.
__global__ __launch_bounds__(256, 8) void dwconv_f(const float* __restrict__ feat,
                                                   const int* __restrict__ nb,
                                                   const float* __restrict__ b2,
                                                   const float* __restrict__ dw,
                                                   const ushort* __restrict__ bx,
                                                   float* __restrict__ out) {
    __shared__ float dwS[NK * NC];
    __shared__ float b2S[NC];
    __shared__ int nbS[32 * NBS2];
    int t = threadIdx.x;
    for (int i = t; i < NK * NC; i += 256) {
        int p = i & 63;
        int ch = ((p >> 1) & 15) + ((p & 1) << 4) + (p & 32);
        dwS[i] = dw[(i & ~63) + ch];
    }
    if (t < NC) b2S[t] = b2[t];
    int b = blockIdx.x;
    int chunk = gridDim.x >> 3;
    int sb = (b & 7) * chunk + (b >> 3);
    const int* nsrc = nb + (size_t)sb * 32 * NK;
    for (int i = t; i < 32 * NK; i += 256) {
        int r = i / NK;
        int k = i - r * NK;
        nbS[r * NBS2 + k] = nsrc[i];
    }
    __syncthreads();

    int r = t >> 3, q = t & 7;
    long row = (long)sb * 32 + r;
    unsigned qo = (unsigned)q << 4;
    const char* bp = (const char*)bx;
    const int* nrow = nbS + r * NBS2;
    const f32x4* wq = (const f32x4*)dwS + q * 2;
    f32x2 acc0 = {0,0}, acc1 = {0,0}, acc2 = {0,0}, acc3 = {0,0};

#pragma unroll
    for (int k = 0; k < NK; ++k) {
        int id = nrow[k];
        int ids = max(id, 0);
        uint4 g = *(const uint4*)(bp + (((unsigned)ids << 7) + qo));
        unsigned m = id >= 0 ? 0xffffffffu : 0u;
        g.x &= m; g.y &= m; g.z &= m; g.w &= m;
        f32x4 wa = wq[k * 16];
        f32x4 wb = wq[k * 16 + 1];
        acc0 += up2(g.x) * (f32x2){wa.x, wa.y};
        acc1 += up2(g.y) * (f32x2){wa.z, wa.w};
        acc2 += up2(g.z) * (f32x2){wb.x, wb.y};
        acc3 += up2(g.w) * (f32x2){wb.z, wb.w};
    }

    int lo_c0 = (q < 4) ? 4 * q : 16 + 4 * q;
    int hi_c0 = lo_c0 + 16;
    const float* fp = feat + row * NC;
    float4 flo = *(const float4*)(fp + lo_c0);
    float4 fhi = *(const float4*)(fp + hi_c0);
    float4 olo = make_float4(acc0.x + flo.x + b2S[lo_c0 + 0],
                             acc1.x + flo.y + b2S[lo_c0 + 1],
                             acc2.x + flo.z + b2S[lo_c0 + 2],
                             acc3.x + flo.w + b2S[lo_c0 + 3]);
    float4 ohi = make_float4(acc0.y + fhi.x + b2S[hi_c0 + 0],
                             acc1.y + fhi.y + b2S[hi_c0 + 1],
                             acc2.y + fhi.z + b2S[hi_c0 + 2],
                             acc3.y + fhi.w + b2S[hi_c0 + 3]);
    *(float4*)(out + row * NC + lo_c0) = olo;
    *(float4*)(out + row * NC + hi_c0) = ohi;
}

extern "C" void kernel_launch(void* const* d_in, const int* in_sizes, int n_in,
                              void* d_out, int out_size, void* d_ws, size_t ws_size,
                              hipStream_t stream) {
    const float* feat = (const float*)d_in[0];
    const int*   nb   = (const int*)d_in[1];
    const float* W    = (const float*)d_in[2];
    const float* b1   = (const float*)d_in[3];
    const float* b2   = (const float*)d_in[4];
    const float* dw   = (const float*)d_in[5];
    float* out = (float*)d_out;
    ushort* bx = (ushort*)d_ws;   // (NPTS+1) x 64 bf16 (permuted), sentinel last

    bool sent = ws_size >= (size_t)(NPTS + 1) * NC * sizeof(ushort);
    uint* zrow = sent ? (uint*)(bx + (size_t)NPTS * NC) : nullptr;

    gemm_mfma<<<2048, 256, 0, stream>>>(feat, W, b1, bx, zrow);
    if (sent)
        dwconv_s<<<NPTS / 32, 256, 0, stream>>>(feat, nb, b2, dw, bx, out);
    else
        dwconv_f<<<NPTS / 32, 256, 0, stream>>>(feat, nb, b2, dw, bx, out);
}